// Round 2
// baseline (5189.653 us; speedup 1.0000x reference)
//
#include <hip/hip_runtime.h>

#define T_LEN 2048
#define BATCH 64
#define IN_DIM 50
#define HID 100
#define G4 400
#define NTAGS 6

__device__ __forceinline__ float sigf(float x) { return 1.0f / (1.0f + expf(-x)); }

// One workgroup per (batch, direction). 512 threads:
//   tid 0..399   : gate-row owners (weights in VGPRs), compute g = (x·Wih + b) + h·Whh
//   tid 448..495 : fused emission partials e[dir][t][b][g] = sum_u wtag[g][dir*100+u] * h[u]
//   tid 496..511 : prefetch next x[t] row into LDS
__global__ __launch_bounds__(512, 2)
void lstm_kernel(const float* __restrict__ x,
                 const float* __restrict__ w_ih_f, const float* __restrict__ w_hh_f,
                 const float* __restrict__ b_ih_f, const float* __restrict__ b_hh_f,
                 const float* __restrict__ w_ih_b, const float* __restrict__ w_hh_b,
                 const float* __restrict__ b_ih_b, const float* __restrict__ b_hh_b,
                 const float* __restrict__ w_tag,
                 float* __restrict__ e_f, float* __restrict__ e_b)
{
    __shared__ float h_lds[HID];
    __shared__ float g_lds[G4];
    __shared__ float xb[2][IN_DIM];

    const int tid = threadIdx.x;
    const int b   = blockIdx.x & 63;
    const int dir = blockIdx.x >> 6;

    const float* wih_p = dir ? w_ih_b : w_ih_f;
    const float* whh_p = dir ? w_hh_b : w_hh_f;
    const float* bih_p = dir ? b_ih_b : b_ih_f;
    const float* bhh_p = dir ? b_hh_b : b_hh_f;
    float* e_p = dir ? e_b : e_f;

    float wih[IN_DIM];
    float whh[HID];
    float bias = 0.0f;
    if (tid < G4) {
        #pragma unroll
        for (int i = 0; i < IN_DIM; ++i) wih[i] = wih_p[tid * IN_DIM + i];
        #pragma unroll
        for (int k = 0; k < HID; ++k) whh[k] = whh_p[tid * HID + k];
        bias = bih_p[tid] + bhh_p[tid];
    }

    const int cw   = tid - 448;                   // emission worker id 0..47
    const int cg   = (cw >= 0) ? (cw >> 3) : 0;   // tag 0..5
    const int cseg = (cw >= 0) ? (cw & 7) : 0;    // segment 0..7 (13 u's each)
    const int u0   = cseg * 13;
    float wt[13];
    if (cw >= 0 && cw < 48) {
        #pragma unroll
        for (int m = 0; m < 13; ++m) {
            int u = u0 + m;
            wt[m] = (u < HID) ? w_tag[cg * 200 + dir * HID + u] : 0.0f;
        }
    }

    float c_reg = 0.0f;
    if (tid < HID) h_lds[tid] = 0.0f;
    const int t0 = dir ? (T_LEN - 1) : 0;
    if (tid < IN_DIM) xb[0][tid] = x[(t0 * BATCH + b) * IN_DIM + tid];
    __syncthreads();

    int cur = 0;
    for (int step = 0; step < T_LEN; ++step) {
        const int t = dir ? (T_LEN - 1 - step) : step;
        if (tid < G4) {
            float xa0 = 0.f, xa1 = 0.f;
            #pragma unroll
            for (int i = 0; i < IN_DIM; i += 2) {
                xa0 += xb[cur][i]     * wih[i];
                xa1 += xb[cur][i + 1] * wih[i + 1];
            }
            float ha0 = 0.f, ha1 = 0.f, ha2 = 0.f, ha3 = 0.f;
            #pragma unroll
            for (int k = 0; k < HID; k += 4) {
                ha0 += h_lds[k]     * whh[k];
                ha1 += h_lds[k + 1] * whh[k + 1];
                ha2 += h_lds[k + 2] * whh[k + 2];
                ha3 += h_lds[k + 3] * whh[k + 3];
            }
            g_lds[tid] = ((xa0 + xa1) + bias) + ((ha0 + ha1) + (ha2 + ha3));
        } else if (cw >= 0 && cw < 48) {
            if (step > 0) {  // emission for the PREVIOUS step's h (still in h_lds)
                const int tp = dir ? (t + 1) : (t - 1);
                float p = 0.f;
                #pragma unroll
                for (int m = 0; m < 13; ++m) {
                    int u = u0 + m;
                    if (u < HID) p += h_lds[u] * wt[m];
                }
                p += __shfl_xor(p, 1);
                p += __shfl_xor(p, 2);
                p += __shfl_xor(p, 4);
                if (cseg == 0) e_p[(tp * BATCH + b) * NTAGS + cg] = p;
            }
        } else if (tid >= 496) {
            const int tn = dir ? (t - 1) : (t + 1);
            if (tn >= 0 && tn < T_LEN) {
                const int li = tid - 496;
                #pragma unroll
                for (int m = 0; m < 4; ++m) {
                    int i = li + 16 * m;
                    if (i < IN_DIM) xb[cur ^ 1][i] = x[(tn * BATCH + b) * IN_DIM + i];
                }
            }
        }
        __syncthreads();
        if (tid < HID) {
            float gi = g_lds[tid];
            float gf = g_lds[HID + tid];
            float gg = g_lds[2 * HID + tid];
            float go = g_lds[3 * HID + tid];
            c_reg = sigf(gf) * c_reg + sigf(gi) * tanhf(gg);
            float h = sigf(go) * tanhf(c_reg);
            h_lds[tid] = h;
        }
        __syncthreads();
        cur ^= 1;
    }
    // emission for the final step's h
    if (cw >= 0 && cw < 48) {
        const int tp = dir ? 0 : (T_LEN - 1);
        float p = 0.f;
        #pragma unroll
        for (int m = 0; m < 13; ++m) {
            int u = u0 + m;
            if (u < HID) p += h_lds[u] * wt[m];
        }
        p += __shfl_xor(p, 1);
        p += __shfl_xor(p, 2);
        p += __shfl_xor(p, 4);
        if (cseg == 0) e_p[(tp * BATCH + b) * NTAGS + cg] = p;
    }
}

// One block (1 wave) per batch. Forward Viterbi scan mimicking the reference's
// fp32 op order exactly; backpointers packed into LDS; backtrace via shfl chain
// 64 rows at a time, emitting one-hot output directly.
__global__ __launch_bounds__(64, 1)
void viterbi_kernel(const float* __restrict__ e_f, const float* __restrict__ e_b,
                    const float* __restrict__ b_tag, const float* __restrict__ start_t,
                    const float* __restrict__ end_t, const float* __restrict__ trans,
                    float* __restrict__ out)
{
    __shared__ unsigned long long bp[T_LEN];   // row k: argmax bytes for step k-1 -> k
    const int b = blockIdx.x;
    const int lane = threadIdx.x;

    float tr[36];
    #pragma unroll
    for (int m = 0; m < 36; ++m) tr[m] = trans[m];
    float bt[6], st[6], en[6];
    #pragma unroll
    for (int j = 0; j < 6; ++j) { bt[j] = b_tag[j]; st[j] = start_t[j]; en[j] = end_t[j]; }

    float sc[6];
    float eN[6];
    {
        int base = (0 * BATCH + b) * NTAGS;
        #pragma unroll
        for (int j = 0; j < 6; ++j) {
            float e0 = (e_f[base + j] + e_b[base + j]) + bt[j];
            sc[j] = st[j] + e0;
        }
    }
    {
        int base = (1 * BATCH + b) * NTAGS;
        #pragma unroll
        for (int j = 0; j < 6; ++j) eN[j] = (e_f[base + j] + e_b[base + j]) + bt[j];
    }

    for (int t = 1; t < T_LEN; ++t) {
        float e[6];
        #pragma unroll
        for (int j = 0; j < 6; ++j) e[j] = eN[j];
        if (t + 1 < T_LEN) {
            int base = ((t + 1) * BATCH + b) * NTAGS;
            #pragma unroll
            for (int j = 0; j < 6; ++j) eN[j] = (e_f[base + j] + e_b[base + j]) + bt[j];
        }
        float ns[6];
        int am[6];
        #pragma unroll
        for (int j = 0; j < 6; ++j) {
            float best = (sc[0] + tr[0 * 6 + j]) + e[j];
            int bi = 0;
            #pragma unroll
            for (int i = 1; i < 6; ++i) {
                float v = (sc[i] + tr[i * 6 + j]) + e[j];
                if (v > best) { best = v; bi = i; }   // strict >: first-max, matches jnp.argmax
            }
            ns[j] = best;
            am[j] = bi;
        }
        unsigned long long pack = 0;
        #pragma unroll
        for (int j = 0; j < 6; ++j) pack |= ((unsigned long long)(unsigned)am[j]) << (8 * j);
        if (lane == 0) bp[t] = pack;
        #pragma unroll
        for (int j = 0; j < 6; ++j) sc[j] = ns[j];
    }

    int tag = 0;
    {
        float best = sc[0] + en[0];
        #pragma unroll
        for (int j = 1; j < 6; ++j) {
            float v = sc[j] + en[j];
            if (v > best) { best = v; tag = j; }
        }
    }
    __syncthreads();

    // Backtrace: 32 super-steps of 64 rows. Lane l holds bp row (kbase - l) in regs;
    // the chain runs through shuffles; each lane records the tag at its own row.
    for (int ss = 0; ss < T_LEN / 64; ++ss) {
        const int kbase = (T_LEN - 1) - ss * 64;
        const int myk = kbase - lane;
        unsigned long long row = (myk >= 1) ? bp[myk] : 0ull;
        unsigned rlo = (unsigned)row;
        unsigned rhi = (unsigned)(row >> 32);
        int mytag = 0;
        for (int s = 0; s < 64; ++s) {
            if (s == lane) mytag = tag;         // tag at time k = kbase - s
            const int k = kbase - s;
            unsigned lo = __shfl(rlo, s);
            unsigned hi = __shfl(rhi, s);
            if (k >= 1) {
                unsigned vv = (tag < 4) ? lo : hi;
                tag = (int)((vv >> ((tag & 3) * 8)) & 0xFFu);   // tag at k-1
            }
        }
        const int o = (myk * BATCH + b) * NTAGS;
        #pragma unroll
        for (int j = 0; j < 6; ++j) out[o + j] = (j == mytag) ? 1.0f : 0.0f;
    }
}

extern "C" void kernel_launch(void* const* d_in, const int* in_sizes, int n_in,
                              void* d_out, int out_size, void* d_ws, size_t ws_size,
                              hipStream_t stream) {
    const float* x       = (const float*)d_in[0];
    const float* w_ih_f  = (const float*)d_in[1];
    const float* w_hh_f  = (const float*)d_in[2];
    const float* b_ih_f  = (const float*)d_in[3];
    const float* b_hh_f  = (const float*)d_in[4];
    const float* w_ih_b  = (const float*)d_in[5];
    const float* w_hh_b  = (const float*)d_in[6];
    const float* b_ih_b  = (const float*)d_in[7];
    const float* b_hh_b  = (const float*)d_in[8];
    const float* w_tag   = (const float*)d_in[9];
    const float* b_tag   = (const float*)d_in[10];
    const float* start_t = (const float*)d_in[11];
    const float* end_t   = (const float*)d_in[12];
    const float* trans   = (const float*)d_in[13];
    float* out = (float*)d_out;

    float* e_f = (float*)d_ws;                         // (T,B,6) fwd emission partials
    float* e_b = e_f + (size_t)T_LEN * BATCH * NTAGS;  // (T,B,6) bwd emission partials

    lstm_kernel<<<dim3(128), dim3(512), 0, stream>>>(
        x, w_ih_f, w_hh_f, b_ih_f, b_hh_f,
        w_ih_b, w_hh_b, b_ih_b, b_hh_b, w_tag, e_f, e_b);

    viterbi_kernel<<<dim3(64), dim3(64), 0, stream>>>(
        e_f, e_b, b_tag, start_t, end_t, trans, out);
}

// Round 5
// 3297.623 us; speedup vs baseline: 1.5738x; 1.5738x over previous
//
#include <hip/hip_runtime.h>

#define T_LEN 2048
#define BATCH 64
#define IN_DIM 50
#define HID 100
#define NTAGS 6

__device__ __forceinline__ float sigf(float x) { return 1.0f / (1.0f + expf(-x)); }

// quad_perm DPP xor-adds (lanes 4u..4u+3 form one unit's chunk quad)
__device__ __forceinline__ float dpp_xor1(float x) {
    int v = __builtin_amdgcn_update_dpp(0, __float_as_int(x), 0xB1, 0xF, 0xF, true);
    return __int_as_float(v);
}
__device__ __forceinline__ float dpp_xor2(float x) {
    int v = __builtin_amdgcn_update_dpp(0, __float_as_int(x), 0x4E, 0xF, 0xF, true);
    return __int_as_float(v);
}

// One workgroup per (batch, direction). 512 threads:
//   tid 0..399   : gate work, thread=(unit u=tid>>2, chunk c=tid&3): owns all 4 gate
//                  rows of unit u over h[25c..25c+25) and x[13c..13c+13) -> 152 wt VGPRs
//   tid 448..495 : fused emission partials (reads h_flat)
//   tid 496..511 : prefetch next x[t] row into LDS
__global__ __launch_bounds__(512, 1)
void lstm_kernel(const float* __restrict__ x,
                 const float* __restrict__ w_ih_f, const float* __restrict__ w_hh_f,
                 const float* __restrict__ b_ih_f, const float* __restrict__ b_hh_f,
                 const float* __restrict__ w_ih_b, const float* __restrict__ w_hh_b,
                 const float* __restrict__ b_ih_b, const float* __restrict__ b_hh_b,
                 const float* __restrict__ w_tag,
                 float* __restrict__ e_f, float* __restrict__ e_b)
{
    __shared__ __align__(16) float h_ch[2][4][28];  // chunked, padded stride 28
    __shared__ __align__(16) float h_flat[2][HID];  // flat copy for emission workers
    __shared__ __align__(16) float xb[2][4][16];    // x chunked: chunk c holds x[13c..13c+12]

    const int tid = threadIdx.x;
    const int b   = blockIdx.x & 63;
    const int dir = blockIdx.x >> 6;

    const float* wih_p = dir ? w_ih_b : w_ih_f;
    const float* whh_p = dir ? w_hh_b : w_hh_f;
    const float* bih_p = dir ? b_ih_b : b_ih_f;
    const float* bhh_p = dir ? b_hh_b : b_hh_f;
    float* e_p = dir ? e_b : e_f;

    // ---- zero ALL of h_ch, h_flat, xb (garbage*0-weight can still be NaN) ----
    {
        float* z1 = &h_ch[0][0][0];    // 224 floats
        if (tid < 224) z1[tid] = 0.0f;
        float* z3 = &xb[0][0][0];      // 128 floats (double-duty lanes)
        if (tid < 128) z3[tid] = 0.0f;
        float* z2 = &h_flat[0][0];     // 200 floats
        if (tid >= 224 && tid < 424) z2[tid - 224] = 0.0f;
    }
    __syncthreads();

    // ---- per-thread setup ----
    const int u = tid >> 2;               // unit 0..99 (valid when tid<400)
    const int c = tid & 3;                // chunk 0..3
    const int uc = u / 25, uo = u % 25;   // h_ch write slot for this unit

    float wx[4][13];
    float wh[4][25];
    float bias4[4];
    if (tid < 400) {
        #pragma unroll
        for (int g = 0; g < 4; ++g) {
            const int row = g * HID + u;
            const float* wri = wih_p + row * IN_DIM;
            #pragma unroll
            for (int m = 0; m < 13; ++m) {
                int i = c * 13 + m;
                wx[g][m] = (i < IN_DIM) ? wri[i] : 0.0f;
            }
            const float* wrh = whh_p + row * HID;
            #pragma unroll
            for (int m = 0; m < 25; ++m) wh[g][m] = wrh[c * 25 + m];
            bias4[g] = bih_p[row] + bhh_p[row];
        }
    }

    const int cw   = tid - 448;                   // emission worker id 0..47
    const int cg   = (cw >= 0) ? (cw >> 3) : 0;   // tag 0..5
    const int cseg = (cw >= 0) ? (cw & 7) : 0;    // segment 0..7 (13 u's each)
    const int u0   = cseg * 13;
    float wt[13];
    if (cw >= 0 && cw < 48) {
        #pragma unroll
        for (int m = 0; m < 13; ++m) {
            int uu = u0 + m;
            wt[m] = (uu < HID) ? w_tag[cg * 200 + dir * HID + uu] : 0.0f;
        }
    }

    // initial x load
    const int t0 = dir ? (T_LEN - 1) : 0;
    if (tid < IN_DIM) xb[0][tid / 13][tid % 13] = x[(t0 * BATCH + b) * IN_DIM + tid];
    __syncthreads();

    float c_reg = 0.0f;
    int cur = 0;
    for (int step = 0; step < T_LEN; ++step) {
        const int t = dir ? (T_LEN - 1 - step) : step;
        const int nxt = cur ^ 1;
        if (tid < 400) {
            // x chunk (13 values, vectorized)
            float4 xq0 = *(const float4*)&xb[cur][c][0];
            float4 xq1 = *(const float4*)&xb[cur][c][4];
            float4 xq2 = *(const float4*)&xb[cur][c][8];
            float x12  = xb[cur][c][12];
            float p0 = 0.f, p1 = 0.f, p2 = 0.f, p3 = 0.f;
            {
                float xv[13] = {xq0.x,xq0.y,xq0.z,xq0.w, xq1.x,xq1.y,xq1.z,xq1.w,
                                xq2.x,xq2.y,xq2.z,xq2.w, x12};
                #pragma unroll
                for (int m = 0; m < 13; ++m) {
                    p0 += xv[m] * wx[0][m];
                    p1 += xv[m] * wx[1][m];
                    p2 += xv[m] * wx[2][m];
                    p3 += xv[m] * wx[3][m];
                }
            }
            // h chunk (25 values): 6 x float4 + 1 scalar, short live ranges
            #pragma unroll
            for (int mb = 0; mb < 6; ++mb) {
                float4 hq = *(const float4*)&h_ch[cur][c][mb * 4];
                float hv[4] = {hq.x, hq.y, hq.z, hq.w};
                #pragma unroll
                for (int l = 0; l < 4; ++l) {
                    p0 += hv[l] * wh[0][mb * 4 + l];
                    p1 += hv[l] * wh[1][mb * 4 + l];
                    p2 += hv[l] * wh[2][mb * 4 + l];
                    p3 += hv[l] * wh[3][mb * 4 + l];
                }
            }
            {
                float h24 = h_ch[cur][c][24];
                p0 += h24 * wh[0][24];
                p1 += h24 * wh[1][24];
                p2 += h24 * wh[2][24];
                p3 += h24 * wh[3][24];
            }
            // cross-chunk quad reduce (DPP): every lane of the quad gets full sums
            p0 += dpp_xor1(p0); p0 += dpp_xor2(p0);
            p1 += dpp_xor1(p1); p1 += dpp_xor2(p1);
            p2 += dpp_xor1(p2); p2 += dpp_xor2(p2);
            p3 += dpp_xor1(p3); p3 += dpp_xor2(p3);
            const float gi = p0 + bias4[0];
            const float gf = p1 + bias4[1];
            const float gg = p2 + bias4[2];
            const float go = p3 + bias4[3];
            c_reg = sigf(gf) * c_reg + sigf(gi) * tanhf(gg);
            const float h = sigf(go) * tanhf(c_reg);
            if (c == 0) {
                h_ch[nxt][uc][uo] = h;
                h_flat[nxt][u]    = h;
            }
        } else if (cw >= 0 && cw < 48) {
            if (step > 0) {  // emission for the PREVIOUS step's h (in h_flat[cur])
                const int tp = dir ? (t + 1) : (t - 1);
                float p = 0.f;
                #pragma unroll
                for (int m = 0; m < 13; ++m) {
                    int uu = u0 + m;
                    if (uu < HID) p += h_flat[cur][uu] * wt[m];
                }
                p += __shfl_xor(p, 1);
                p += __shfl_xor(p, 2);
                p += __shfl_xor(p, 4);
                if (cseg == 0) e_p[(tp * BATCH + b) * NTAGS + cg] = p;
            }
        } else if (tid >= 496) {
            const int tn = dir ? (t - 1) : (t + 1);
            if (tn >= 0 && tn < T_LEN) {
                const int li = tid - 496;
                #pragma unroll
                for (int m = 0; m < 4; ++m) {
                    int i = li + 16 * m;
                    if (i < IN_DIM) xb[nxt][i / 13][i % 13] = x[(tn * BATCH + b) * IN_DIM + i];
                }
            }
        }
        __syncthreads();
        cur = nxt;
    }
    // emission for the final step's h
    if (cw >= 0 && cw < 48) {
        const int tp = dir ? 0 : (T_LEN - 1);
        float p = 0.f;
        #pragma unroll
        for (int m = 0; m < 13; ++m) {
            int uu = u0 + m;
            if (uu < HID) p += h_flat[cur][uu] * wt[m];
        }
        p += __shfl_xor(p, 1);
        p += __shfl_xor(p, 2);
        p += __shfl_xor(p, 4);
        if (cseg == 0) e_p[(tp * BATCH + b) * NTAGS + cg] = p;
    }
}

// One block (1 wave) per batch. Lanes 0..5 run the scan in parallel (lane j owns
// column j) with a depth-8 emission register pipeline; backpointer bytes to LDS;
// backtrace via shfl chain 64 rows at a time, emitting one-hot output directly.
__global__ __launch_bounds__(64, 1)
void viterbi_kernel(const float* __restrict__ e_f, const float* __restrict__ e_b,
                    const float* __restrict__ b_tag, const float* __restrict__ start_t,
                    const float* __restrict__ end_t, const float* __restrict__ trans,
                    float* __restrict__ out)
{
    __shared__ __align__(8) unsigned char bpb[T_LEN][8];  // row t: argmax byte per tag
    const int b    = blockIdx.x;
    const int lane = threadIdx.x;
    const int j    = (lane < 6) ? lane : 5;   // clamp: lanes >=6 shadow column 5

    float trc[6];
    #pragma unroll
    for (int i = 0; i < 6; ++i) trc[i] = trans[i * 6 + j];
    const float btj = b_tag[j];
    const float stj = start_t[j];
    const float enj = end_t[j];

    // prime depth-8 pipeline with e[1..8]
    float pf[8], pb[8];
    #pragma unroll
    for (int d = 0; d < 8; ++d) {
        const int t = 1 + d;
        pf[d] = e_f[(t * BATCH + b) * NTAGS + j];
        pb[d] = e_b[(t * BATCH + b) * NTAGS + j];
    }
    float scj;
    {
        const float ef0 = e_f[(0 * BATCH + b) * NTAGS + j];
        const float eb0 = e_b[(0 * BATCH + b) * NTAGS + j];
        scj = stj + ((ef0 + eb0) + btj);
    }
    float sc[6];
    #pragma unroll
    for (int i = 0; i < 6; ++i) sc[i] = __shfl(scj, i);

    for (int t = 1; t < T_LEN; ++t) {
        const float ej = (pf[0] + pb[0]) + btj;
        #pragma unroll
        for (int d = 0; d < 7; ++d) { pf[d] = pf[d + 1]; pb[d] = pb[d + 1]; }
        {
            int tl = t + 8; if (tl > T_LEN - 1) tl = T_LEN - 1;
            pf[7] = e_f[(tl * BATCH + b) * NTAGS + j];
            pb[7] = e_b[(tl * BATCH + b) * NTAGS + j];
        }
        float best = (sc[0] + trc[0]) + ej;
        int bi = 0;
        #pragma unroll
        for (int i = 1; i < 6; ++i) {
            float v = (sc[i] + trc[i]) + ej;
            if (v > best) { best = v; bi = i; }   // strict >: first-max, matches jnp.argmax
        }
        if (lane < 8) bpb[t][lane] = (unsigned char)bi;
        scj = best;
        #pragma unroll
        for (int i = 0; i < 6; ++i) sc[i] = __shfl(scj, i);
    }

    // final tag: argmax_j (sc[j] + end[j]) with first-max semantics
    int tag = 0;
    {
        const float fv = scj + enj;
        float bb = __shfl(fv, 0);
        #pragma unroll
        for (int i = 1; i < 6; ++i) {
            float v = __shfl(fv, i);
            if (v > bb) { bb = v; tag = i; }
        }
    }
    __syncthreads();

    // Backtrace: 32 super-steps of 64 rows. Lane l holds bp row (kbase - l) in regs;
    // the chain runs through shuffles; each lane records the tag at its own row.
    for (int ss = 0; ss < T_LEN / 64; ++ss) {
        const int kbase = (T_LEN - 1) - ss * 64;
        const int myk = kbase - lane;
        unsigned long long row = (myk >= 1) ? *(const unsigned long long*)&bpb[myk][0] : 0ull;
        unsigned rlo = (unsigned)row;
        unsigned rhi = (unsigned)(row >> 32);
        int mytag = 0;
        for (int s = 0; s < 64; ++s) {
            if (s == lane) mytag = tag;          // tag at time k = kbase - s
            const int k = kbase - s;
            unsigned lo = __shfl(rlo, s);
            unsigned hi = __shfl(rhi, s);
            if (k >= 1) {
                unsigned vv = (tag < 4) ? lo : hi;
                tag = (int)((vv >> ((tag & 3) * 8)) & 0xFFu);   // tag at k-1
            }
        }
        const int o = (myk * BATCH + b) * NTAGS;
        #pragma unroll
        for (int jj = 0; jj < 6; ++jj) out[o + jj] = (jj == mytag) ? 1.0f : 0.0f;
    }
}

extern "C" void kernel_launch(void* const* d_in, const int* in_sizes, int n_in,
                              void* d_out, int out_size, void* d_ws, size_t ws_size,
                              hipStream_t stream) {
    const float* x       = (const float*)d_in[0];
    const float* w_ih_f  = (const float*)d_in[1];
    const float* w_hh_f  = (const float*)d_in[2];
    const float* b_ih_f  = (const float*)d_in[3];
    const float* b_hh_f  = (const float*)d_in[4];
    const float* w_ih_b  = (const float*)d_in[5];
    const float* w_hh_b  = (const float*)d_in[6];
    const float* b_ih_b  = (const float*)d_in[7];
    const float* b_hh_b  = (const float*)d_in[8];
    const float* w_tag   = (const float*)d_in[9];
    const float* b_tag   = (const float*)d_in[10];
    const float* start_t = (const float*)d_in[11];
    const float* end_t   = (const float*)d_in[12];
    const float* trans   = (const float*)d_in[13];
    float* out = (float*)d_out;

    float* e_f = (float*)d_ws;                         // (T,B,6) fwd emission partials
    float* e_b = e_f + (size_t)T_LEN * BATCH * NTAGS;  // (T,B,6) bwd emission partials

    lstm_kernel<<<dim3(128), dim3(512), 0, stream>>>(
        x, w_ih_f, w_hh_f, b_ih_f, b_hh_f,
        w_ih_b, w_hh_b, b_ih_b, b_hh_b, w_tag, e_f, e_b);

    viterbi_kernel<<<dim3(64), dim3(64), 0, stream>>>(
        e_f, e_b, b_tag, start_t, end_t, trans, out);
}